// Round 6
// baseline (395.846 us; speedup 1.0000x reference)
//
#include <hip/hip_runtime.h>
#include <math.h>

#define EMBED 1024
#define NHEAD 16
#define HDIM  64
#define SEQT  2048
#define BATCH 4

typedef __bf16 bf16x4 __attribute__((ext_vector_type(4)));
typedef __bf16 bf16x8 __attribute__((ext_vector_type(8)));
typedef float  f32x4  __attribute__((ext_vector_type(4)));
typedef unsigned short u16x8 __attribute__((ext_vector_type(8)));

#define AS1 __attribute__((address_space(1)))
#define AS3 __attribute__((address_space(3)))
// async global->LDS, 16B per lane (guide §5: width=16, m97-verified)
#define GLD_LDS16(gp, lp) __builtin_amdgcn_global_load_lds( \
    (const AS1 unsigned int*)(gp), (AS3 unsigned int*)(lp), 16, 0, 0)

// log2(e) / sqrt(HDIM): folded into Q at QKV-epilogue so scores are exp2-ready
#define QSCALE 0.180336880f

// native cast (v_cvt_pk_bf16_f32 on gfx950)
__device__ __forceinline__ unsigned short f2bf_hw(float f) {
    union { __bf16 h; unsigned short u; } c; c.h = (__bf16)f; return c.u;
}

// one launch converts x, W_qkv, W_proj (fp32 -> bf16), in float4 units
__global__ __launch_bounds__(256)
void cvt_all(const float* __restrict__ x, const float* __restrict__ wq,
             const float* __restrict__ wp,
             unsigned short* __restrict__ xb, unsigned short* __restrict__ wqb,
             unsigned short* __restrict__ wpb)
{
    const int N1 = 2097152;            // 8192*1024/4
    const int N2 = 786432;             // 3*1024*1024/4
    int i = blockIdx.x * 256 + threadIdx.x;
    const float4* src; ushort4* dst; int j;
    if (i < N1)            { src = (const float4*)x;  dst = (ushort4*)xb;  j = i; }
    else if (i < N1 + N2)  { src = (const float4*)wq; dst = (ushort4*)wqb; j = i - N1; }
    else                   { src = (const float4*)wp; dst = (ushort4*)wpb; j = i - N1 - N2; }
    float4 v = src[j];
    ushort4 o;
    o.x = f2bf_hw(v.x); o.y = f2bf_hw(v.y); o.z = f2bf_hw(v.z); o.w = f2bf_hw(v.w);
    dst[j] = o;
}

// ---------------- bf16 MFMA GEMM (R5: BK=64, frozen) ----------------
// 128x128 tile, BK=64, 2x2 waves, 4x4 accs x2 K-slices. 2-phase skeleton;
// family closed at ~550 TF (R4: conflicts off critical path; R5: sync
// frequency ~null). Do not touch.
template<int MODE>
__global__ __launch_bounds__(256)
void gemm_bt_mfma(const unsigned short* __restrict__ A, const unsigned short* __restrict__ Bw,
                  const float* __restrict__ bias,
                  void* out0, void* out1, void* out2,
                  int M, int N, int K)
{
    __shared__ __align__(16) unsigned short Asm[2][128 * 64];   // 2 x 16 KB
    __shared__ __align__(16) unsigned short Bsm[2][128 * 64];   // 2 x 16 KB

    const int tid  = threadIdx.x;
    const int lane = tid & 63;
    const int wave = tid >> 6;
    const int wm = wave >> 1, wn = wave & 1;
    const int col = lane & 15, quad = lane >> 4;
    const long m0 = (long)blockIdx.y * 128, n0 = (long)blockIdx.x * 128;

    f32x4 acc[4][4];
#pragma unroll
    for (int mi = 0; mi < 4; mi++)
#pragma unroll
        for (int ni = 0; ni < 4; ni++) acc[mi][ni] = (f32x4){0.f, 0.f, 0.f, 0.f};

    const int srow  = tid >> 3;                    // 0..31
    const int gslot = (tid & 7) ^ (srow & 7);      // pre-swizzled source slot
    const unsigned short* Ag = A  + (m0 + srow) * K + gslot * 8;
    const unsigned short* Bg = Bw + (n0 + srow) * K + gslot * 8;

#define STAGE(buf_, kk_) do { \
    _Pragma("unroll") for (int r_ = 0; r_ < 4; r_++) { \
        GLD_LDS16(Ag + (long)(r_ * 32) * K + (kk_), &Asm[buf_][0] + r_ * 2048 + tid * 8); \
        GLD_LDS16(Bg + (long)(r_ * 32) * K + (kk_), &Bsm[buf_][0] + r_ * 2048 + tid * 8); \
    } } while (0)

    const int cs0 = ((quad    ) ^ (col & 7)) * 8;  // K-slice 0
    const int cs1 = ((quad + 4) ^ (col & 7)) * 8;  // K-slice 1

    STAGE(0, 0);

    const int iters = K >> 6;
    for (int it = 0; it < iters; it++) {
        const int cur = it & 1;
        __builtin_amdgcn_s_waitcnt(0x0F70);   // vmcnt(0): tile `it` staged
        __syncthreads();
        if (it + 1 < iters)
            STAGE(cur ^ 1, (it + 1) * 64);

        bf16x8 af[4][2], bf[4][2];
#pragma unroll
        for (int mi = 0; mi < 4; mi++) {
            const int row = wm * 64 + mi * 16 + col;
            af[mi][0] = *(const bf16x8*)&Asm[cur][row * 64 + cs0];
            af[mi][1] = *(const bf16x8*)&Asm[cur][row * 64 + cs1];
        }
#pragma unroll
        for (int ni = 0; ni < 4; ni++) {
            const int row = wn * 64 + ni * 16 + col;
            bf[ni][0] = *(const bf16x8*)&Bsm[cur][row * 64 + cs0];
            bf[ni][1] = *(const bf16x8*)&Bsm[cur][row * 64 + cs1];
        }
#pragma unroll
        for (int mi = 0; mi < 4; mi++)
#pragma unroll
            for (int ni = 0; ni < 4; ni++) {
                acc[mi][ni] = __builtin_amdgcn_mfma_f32_16x16x32_bf16(af[mi][0], bf[ni][0], acc[mi][ni], 0, 0, 0);
                acc[mi][ni] = __builtin_amdgcn_mfma_f32_16x16x32_bf16(af[mi][1], bf[ni][1], acc[mi][ni], 0, 0, 0);
            }
    }
#undef STAGE

    // epilogue: C/D layout col=lane&15, row=quad*4+r (m89/m91-verified)
#pragma unroll
    for (int mi = 0; mi < 4; mi++) {
#pragma unroll
        for (int ni = 0; ni < 4; ni++) {
            long n = n0 + wn * 64 + ni * 16 + col;
            float bv = bias[n];
#pragma unroll
            for (int r = 0; r < 4; r++) {
                long m = m0 + wm * 64 + mi * 16 + quad * 4 + r;
                float v = acc[mi][ni][r] + bv;
                if (MODE == 0) {
                    ((float*)out0)[m * N + n] = v;
                } else {
                    int which = (int)(n >> 10);
                    int c = (int)(n & 1023);
                    int h = c >> 6, d = c & 63;
                    int b = (int)(m >> 11), t = (int)(m & 2047);
                    long bh = (long)(b * NHEAD + h);
                    if (which == 0)      ((unsigned short*)out0)[(bh * SEQT + t) * HDIM + d] = f2bf_hw(v * QSCALE);
                    else if (which == 1) ((unsigned short*)out1)[(bh * SEQT + t) * HDIM + d] = f2bf_hw(v);
                    else                 ((unsigned short*)out2)[(bh * HDIM + d) * SEQT + t] = f2bf_hw(v);
                }
            }
        }
    }
}

// ---------------- bf16 MFMA flash attention v5: T14 reg-staging, 4 blocks/CU ----
// Q-tile 128; 4 waves x 32 q-rows. Single-buffered K/V (LDS 35.3 KB -> 4
// blocks/CU = full residency for the 1024-block grid, +33% TLP for latency
// hiding). Staging is T14 async-split (m214 v27, +17%): 4x16B global loads
// into REGS issued at k-tile top (hide HBM/L3 latency under QK+softmax+PV),
// ds_write after the tile-close barrier, second barrier makes them visible.
// Same swizzled K/V layout as before (write-side applies slot^(row&7)).
// Grid load-balance: qt pairs long+short groups (g&1 ? g>>1 : 15-(g>>1)) so
// each CU's 4 resident blocks sum to ~68 k-tiles (was 80 vs 56).
#define PPAD 72

__global__ __launch_bounds__(256, 4)
void flash_attn_mfma5(const unsigned short* __restrict__ Qb,
                      const unsigned short* __restrict__ Kb,
                      const unsigned short* __restrict__ Vt,
                      unsigned short* __restrict__ Ob)
{
    __shared__ __align__(16) unsigned short P_lds[128 * PPAD];    // 18432 B
    __shared__ __align__(16) unsigned short K_lds[64 * 64];       // 8 KB
    __shared__ __align__(16) unsigned short V_lds[64 * 64];       // 8 KB
    __shared__ __align__(16) float L_lds[128];                    // 512 B

    const int tid  = threadIdx.x;
    const int lane = tid & 63;
    const int wave = tid >> 6;
    const int col  = lane & 15;
    const int quad = lane >> 4;

    const int idx = blockIdx.x;
    const int g = idx >> 6;
    const int qt = (g & 1) ? (g >> 1) : (15 - (g >> 1));   // balanced long/short
    const int hb = idx & 63;
    const int h = hb & 15, b = hb >> 4;
    const int q0 = qt * 128;
    const long bh = (long)(b * NHEAD + h);
    const unsigned short* Kbh = Kb + bh * SEQT * HDIM;
    const unsigned short* Vbh = Vt + bh * HDIM * SEQT;
    const int ktiles = 2 * qt + 2;

    // staging geometry: thread covers K/V rows r0, r0+32 at 16B slot (tid&7).
    const int r0   = tid >> 3;            // 0..31
    const int slot = tid & 7;
    const int ws   = (slot ^ (r0 & 7)) * 8;    // swizzled write slot (elems)
    unsigned short* kw0 = &K_lds[r0 * 64 + ws];
    unsigned short* kw1 = &K_lds[(r0 + 32) * 64 + ws];   // (r0+32)&7 == r0&7
    unsigned short* vw0 = &V_lds[r0 * 64 + ws];
    unsigned short* vw1 = &V_lds[(r0 + 32) * 64 + ws];
    const unsigned short* Kg0 = Kbh + r0 * HDIM + slot * 8;
    const unsigned short* Kg1 = Kbh + (r0 + 32) * HDIM + slot * 8;
    const unsigned short* Vg0 = Vbh + (long)r0 * SEQT + slot * 8;
    const unsigned short* Vg1 = Vbh + (long)(r0 + 32) * SEQT + slot * 8;

    bf16x8 qf[2][2];
#pragma unroll
    for (int ni = 0; ni < 2; ni++) {
        const unsigned short* qrow = Qb + (bh * SEQT + q0 + wave * 32 + ni * 16 + col) * HDIM;
        qf[ni][0] = *(const bf16x8*)(qrow + quad * 8);
        qf[ni][1] = *(const bf16x8*)(qrow + 32 + quad * 8);
    }

    // prologue: tile 0 via regs -> LDS
    {
        u16x8 kr0 = *(const u16x8*)Kg0;
        u16x8 kr1 = *(const u16x8*)Kg1;
        u16x8 vr0 = *(const u16x8*)Vg0;
        u16x8 vr1 = *(const u16x8*)Vg1;
        *(u16x8*)kw0 = kr0; *(u16x8*)kw1 = kr1;
        *(u16x8*)vw0 = vr0; *(u16x8*)vw1 = vr1;
    }
    __syncthreads();

    f32x4 o[2][4];
#pragma unroll
    for (int mi = 0; mi < 2; mi++)
#pragma unroll
        for (int dt = 0; dt < 4; dt++) o[mi][dt] = (f32x4){0.f, 0.f, 0.f, 0.f};
    float rs[2] = {0.f, 0.f};

    const int cswz0 = quad ^ (col & 7);
    const int cswz1 = (quad + 4) ^ (col & 7);

    u16x8 kr0, kr1, vr0, vr1;
    for (int kt = 0; kt < ktiles; kt++) {
        // T14 issue-early: next tile's 4x16B into regs; pin at loop top
        if (kt + 1 < ktiles) {
            const int t1 = (kt + 1) * 64;
            kr0 = *(const u16x8*)(Kg0 + (long)t1 * HDIM);
            kr1 = *(const u16x8*)(Kg1 + (long)t1 * HDIM);
            vr0 = *(const u16x8*)(Vg0 + t1);
            vr1 = *(const u16x8*)(Vg1 + t1);
        }
        __builtin_amdgcn_sched_barrier(0);

        // S^T = K Q^T : A = K (m=key), B = Q (n=query). C: col=q, row=key.
        f32x4 st[4][2];
        __builtin_amdgcn_s_setprio(1);
#pragma unroll
        for (int mt = 0; mt < 4; mt++) {
            const int row = mt * 16 + col;
            bf16x8 kf0 = *(const bf16x8*)&K_lds[row * 64 + cswz0 * 8];
            bf16x8 kf1 = *(const bf16x8*)&K_lds[row * 64 + cswz1 * 8];
#pragma unroll
            for (int ni = 0; ni < 2; ni++) {
                f32x4 acc = (f32x4){0.f, 0.f, 0.f, 0.f};
                acc = __builtin_amdgcn_mfma_f32_16x16x32_bf16(kf0, qf[ni][0], acc, 0, 0, 0);
                acc = __builtin_amdgcn_mfma_f32_16x16x32_bf16(kf1, qf[ni][1], acc, 0, 0, 0);
                st[mt][ni] = acc;
            }
        }
        __builtin_amdgcn_s_setprio(0);
        const int k0 = kt * 64;
        if (kt >= 2 * qt) {                // diagonal tiles: mask key > q
#pragma unroll
            for (int mt = 0; mt < 4; mt++) {
                const int keybase = k0 + mt * 16 + quad * 4;
#pragma unroll
                for (int ni = 0; ni < 2; ni++) {
                    const int qg = q0 + wave * 32 + ni * 16 + col;
#pragma unroll
                    for (int r = 0; r < 4; r++)
                        if (keybase + r > qg) st[mt][ni][r] = -INFINITY;
                }
            }
        }

        // p = exp2(s); accumulate row-sum partials; packed b64 P-store
#pragma unroll
        for (int mt = 0; mt < 4; mt++)
#pragma unroll
            for (int ni = 0; ni < 2; ni++) {
                f32x4 p;
#pragma unroll
                for (int r = 0; r < 4; r++) p[r] = __builtin_amdgcn_exp2f(st[mt][ni][r]);
                rs[ni] += (p[0] + p[1]) + (p[2] + p[3]);
                bf16x4 pb = __builtin_convertvector(p, bf16x4);
                *(bf16x4*)&P_lds[(wave * 32 + ni * 16 + col) * PPAD + mt * 16 + quad * 4] = pb;
            }

        // PV: A = P[q][k] (wave-private rows), B = V^T
        __builtin_amdgcn_s_setprio(1);
#pragma unroll
        for (int mi = 0; mi < 2; mi++) {
            const unsigned short* prow = &P_lds[(wave * 32 + mi * 16 + col) * PPAD];
            bf16x8 pf0 = *(const bf16x8*)(prow + quad * 8);
            bf16x8 pf1 = *(const bf16x8*)(prow + 32 + quad * 8);
#pragma unroll
            for (int dt = 0; dt < 4; dt++) {
                const int row = dt * 16 + col;
                bf16x8 vf0 = *(const bf16x8*)&V_lds[row * 64 + cswz0 * 8];
                bf16x8 vf1 = *(const bf16x8*)&V_lds[row * 64 + cswz1 * 8];
                o[mi][dt] = __builtin_amdgcn_mfma_f32_16x16x32_bf16(pf0, vf0, o[mi][dt], 0, 0, 0);
                o[mi][dt] = __builtin_amdgcn_mfma_f32_16x16x32_bf16(pf1, vf1, o[mi][dt], 0, 0, 0);
            }
        }
        __builtin_amdgcn_s_setprio(0);

        // tile close: all waves done reading K/V; write-late the staged regs
        __syncthreads();
        if (kt + 1 < ktiles) {
            *(u16x8*)kw0 = kr0; *(u16x8*)kw1 = kr1;
            *(u16x8*)vw0 = vr0; *(u16x8*)vw1 = vr1;
        }
        __syncthreads();
    }

    // final row-sum reduction over quads (partials partitioned by quad)
#pragma unroll
    for (int ni = 0; ni < 2; ni++) {
        rs[ni] += __shfl_xor(rs[ni], 16);
        rs[ni] += __shfl_xor(rs[ni], 32);
        if (quad == 0) L_lds[wave * 32 + ni * 16 + col] = rs[ni];
    }
    __syncthreads();
    f32x4 lf[2];
#pragma unroll
    for (int mi = 0; mi < 2; mi++)
        lf[mi] = *(const f32x4*)&L_lds[wave * 32 + mi * 16 + quad * 4];

    // epilogue: bf16 Ob[b][t][h*64+d]
#pragma unroll
    for (int mi = 0; mi < 2; mi++)
#pragma unroll
        for (int r = 0; r < 4; r++) {
            float inv = 1.f / lf[mi][r];
            int t = q0 + wave * 32 + mi * 16 + quad * 4 + r;
            unsigned short* orow = Ob + ((long)(b * SEQT + t)) * EMBED + h * HDIM;
#pragma unroll
            for (int dt = 0; dt < 4; dt++)
                orow[dt * 16 + col] = f2bf_hw(o[mi][dt][r] * inv);
        }
}

extern "C" void kernel_launch(void* const* d_in, const int* in_sizes, int n_in,
                              void* d_out, int out_size, void* d_ws, size_t ws_size,
                              hipStream_t stream)
{
    const float* x     = (const float*)d_in[0];
    const float* Wqkv  = (const float*)d_in[1];
    const float* bqkv  = (const float*)d_in[2];
    const float* Wproj = (const float*)d_in[3];
    const float* bproj = (const float*)d_in[4];
    float* out = (float*)d_out;

    const long Mbt = (long)BATCH * SEQT;                 // 8192
    const long per = (long)BATCH * NHEAD * SEQT * HDIM;  // 8,388,608 elems

    unsigned short* xb  = (unsigned short*)d_ws;
    unsigned short* wqb = xb  + per;
    unsigned short* wpb = wqb + 3 * EMBED * EMBED;
    unsigned short* Qb  = wpb + EMBED * EMBED;           // bf16 [bh][t][d], pre-scaled
    unsigned short* Kb  = Qb + per;
    unsigned short* Vt  = Kb + per;                      // bf16 [bh][d][t]
    unsigned short* Ob  = Vt + per;                      // bf16 [B,T,C]

    cvt_all<<<12288, 256, 0, stream>>>(x, Wqkv, Wproj, xb, wqb, wpb);

    dim3 g1(3 * EMBED / 128, Mbt / 128);
    gemm_bt_mfma<1><<<g1, 256, 0, stream>>>(xb, wqb, bqkv, Qb, Kb, Vt,
                                            (int)Mbt, 3 * EMBED, EMBED);

    flash_attn_mfma5<<<1024, 256, 0, stream>>>(Qb, Kb, Vt, Ob);

    dim3 g3(EMBED / 128, Mbt / 128);
    gemm_bt_mfma<0><<<g3, 256, 0, stream>>>(Ob, wpb, bproj, out, nullptr, nullptr,
                                            (int)Mbt, EMBED, EMBED);
}

// Round 7
// 256.874 us; speedup vs baseline: 1.5410x; 1.5410x over previous
//
#include <hip/hip_runtime.h>
#include <math.h>

#define EMBED 1024
#define NHEAD 16
#define HDIM  64
#define SEQT  2048
#define BATCH 4

typedef __bf16 bf16x4 __attribute__((ext_vector_type(4)));
typedef __bf16 bf16x8 __attribute__((ext_vector_type(8)));
typedef float  f32x4  __attribute__((ext_vector_type(4)));
typedef float  f32x16 __attribute__((ext_vector_type(16)));

#define AS1 __attribute__((address_space(1)))
#define AS3 __attribute__((address_space(3)))
// async global->LDS, 16B per lane (guide §5: width=16, m97-verified)
#define GLD_LDS16(gp, lp) __builtin_amdgcn_global_load_lds( \
    (const AS1 unsigned int*)(gp), (AS3 unsigned int*)(lp), 16, 0, 0)

// log2(e) / sqrt(HDIM): folded into Q at QKV-epilogue so scores are exp2-ready
#define QSCALE 0.180336880f

// native cast (v_cvt_pk_bf16_f32 on gfx950)
__device__ __forceinline__ unsigned short f2bf_hw(float f) {
    union { __bf16 h; unsigned short u; } c; c.h = (__bf16)f; return c.u;
}
// pack two f32 -> one dword of 2 bf16 (compiler emits cvt_pk; m240: don't hand-asm)
__device__ __forceinline__ unsigned pk2(float a, float b) {
    union { __bf16 h[2]; unsigned u; } c; c.h[0] = (__bf16)a; c.h[1] = (__bf16)b; return c.u;
}

// one launch converts x, W_qkv, W_proj (fp32 -> bf16), in float4 units
__global__ __launch_bounds__(256)
void cvt_all(const float* __restrict__ x, const float* __restrict__ wq,
             const float* __restrict__ wp,
             unsigned short* __restrict__ xb, unsigned short* __restrict__ wqb,
             unsigned short* __restrict__ wpb)
{
    const int N1 = 2097152;            // 8192*1024/4
    const int N2 = 786432;             // 3*1024*1024/4
    int i = blockIdx.x * 256 + threadIdx.x;
    const float4* src; ushort4* dst; int j;
    if (i < N1)            { src = (const float4*)x;  dst = (ushort4*)xb;  j = i; }
    else if (i < N1 + N2)  { src = (const float4*)wq; dst = (ushort4*)wqb; j = i - N1; }
    else                   { src = (const float4*)wp; dst = (ushort4*)wpb; j = i - N1 - N2; }
    float4 v = src[j];
    ushort4 o;
    o.x = f2bf_hw(v.x); o.y = f2bf_hw(v.y); o.z = f2bf_hw(v.z); o.w = f2bf_hw(v.w);
    dst[j] = o;
}

// ---------------- bf16 MFMA GEMM (R5: BK=64, frozen) ----------------
// 128x128 tile, BK=64, 2x2 waves, 4x4 accs x2 K-slices. 2-phase skeleton;
// family closed at ~550 TF (R4: conflicts off critical path; R5: sync
// frequency ~null). Do not touch.
template<int MODE>
__global__ __launch_bounds__(256)
void gemm_bt_mfma(const unsigned short* __restrict__ A, const unsigned short* __restrict__ Bw,
                  const float* __restrict__ bias,
                  void* out0, void* out1, void* out2,
                  int M, int N, int K)
{
    __shared__ __align__(16) unsigned short Asm[2][128 * 64];   // 2 x 16 KB
    __shared__ __align__(16) unsigned short Bsm[2][128 * 64];   // 2 x 16 KB

    const int tid  = threadIdx.x;
    const int lane = tid & 63;
    const int wave = tid >> 6;
    const int wm = wave >> 1, wn = wave & 1;
    const int col = lane & 15, quad = lane >> 4;
    const long m0 = (long)blockIdx.y * 128, n0 = (long)blockIdx.x * 128;

    f32x4 acc[4][4];
#pragma unroll
    for (int mi = 0; mi < 4; mi++)
#pragma unroll
        for (int ni = 0; ni < 4; ni++) acc[mi][ni] = (f32x4){0.f, 0.f, 0.f, 0.f};

    const int srow  = tid >> 3;                    // 0..31
    const int gslot = (tid & 7) ^ (srow & 7);      // pre-swizzled source slot
    const unsigned short* Ag = A  + (m0 + srow) * K + gslot * 8;
    const unsigned short* Bg = Bw + (n0 + srow) * K + gslot * 8;

#define STAGE(buf_, kk_) do { \
    _Pragma("unroll") for (int r_ = 0; r_ < 4; r_++) { \
        GLD_LDS16(Ag + (long)(r_ * 32) * K + (kk_), &Asm[buf_][0] + r_ * 2048 + tid * 8); \
        GLD_LDS16(Bg + (long)(r_ * 32) * K + (kk_), &Bsm[buf_][0] + r_ * 2048 + tid * 8); \
    } } while (0)

    const int cs0 = ((quad    ) ^ (col & 7)) * 8;  // K-slice 0
    const int cs1 = ((quad + 4) ^ (col & 7)) * 8;  // K-slice 1

    STAGE(0, 0);

    const int iters = K >> 6;
    for (int it = 0; it < iters; it++) {
        const int cur = it & 1;
        __builtin_amdgcn_s_waitcnt(0x0F70);   // vmcnt(0): tile `it` staged
        __syncthreads();
        if (it + 1 < iters)
            STAGE(cur ^ 1, (it + 1) * 64);

        bf16x8 af[4][2], bf[4][2];
#pragma unroll
        for (int mi = 0; mi < 4; mi++) {
            const int row = wm * 64 + mi * 16 + col;
            af[mi][0] = *(const bf16x8*)&Asm[cur][row * 64 + cs0];
            af[mi][1] = *(const bf16x8*)&Asm[cur][row * 64 + cs1];
        }
#pragma unroll
        for (int ni = 0; ni < 4; ni++) {
            const int row = wn * 64 + ni * 16 + col;
            bf[ni][0] = *(const bf16x8*)&Bsm[cur][row * 64 + cs0];
            bf[ni][1] = *(const bf16x8*)&Bsm[cur][row * 64 + cs1];
        }
#pragma unroll
        for (int mi = 0; mi < 4; mi++)
#pragma unroll
            for (int ni = 0; ni < 4; ni++) {
                acc[mi][ni] = __builtin_amdgcn_mfma_f32_16x16x32_bf16(af[mi][0], bf[ni][0], acc[mi][ni], 0, 0, 0);
                acc[mi][ni] = __builtin_amdgcn_mfma_f32_16x16x32_bf16(af[mi][1], bf[ni][1], acc[mi][ni], 0, 0, 0);
            }
    }
#undef STAGE

    // epilogue: C/D layout col=lane&15, row=quad*4+r (m89/m91-verified)
#pragma unroll
    for (int mi = 0; mi < 4; mi++) {
#pragma unroll
        for (int ni = 0; ni < 4; ni++) {
            long n = n0 + wn * 64 + ni * 16 + col;
            float bv = bias[n];
#pragma unroll
            for (int r = 0; r < 4; r++) {
                long m = m0 + wm * 64 + mi * 16 + quad * 4 + r;
                float v = acc[mi][ni][r] + bv;
                if (MODE == 0) {
                    ((float*)out0)[m * N + n] = v;
                } else {
                    int which = (int)(n >> 10);
                    int c = (int)(n & 1023);
                    int h = c >> 6, d = c & 63;
                    int b = (int)(m >> 11), t = (int)(m & 2047);
                    long bh = (long)(b * NHEAD + h);
                    if (which == 0)      ((unsigned short*)out0)[(bh * SEQT + t) * HDIM + d] = f2bf_hw(v * QSCALE);
                    else if (which == 1) ((unsigned short*)out1)[(bh * SEQT + t) * HDIM + d] = f2bf_hw(v);
                    else                 ((unsigned short*)out2)[(bh * HDIM + d) * SEQT + t] = f2bf_hw(v);
                }
            }
        }
    }
}

// ---------------- bf16 MFMA flash attention v6: 32x32 swapped, reg-P ----------
// Q-tile 128; 4 waves x 32 q-rows (QBLK=32/wave, m214 architecture). QK^T as
// mfma_32x32x16(A=K, B=Q): C[m=key][n=q] -> lane holds P[q=lane&31][32 keys]
// across st0 (keys 0-31) / st1 (32-63), row = (reg&3)+8*(reg>>2)+4*(lane>>5)
// (m74/m101-verified). No-max softmax (v4 numerics). P NEVER touches LDS:
// PV B-frags built in-register with 16 pk2 + 8 shfl_xor(32)/tile (T12
// mechanism; element mapping verified: target lane hi needs keys 16c+8*hi+
// {0..7}; first 4 from the lane's q-half (srcHi=0 = lanes<32), last 4 from
// the partner lane^32). PV as mfma(A=V^T, B=P): C[m=d][n=q] — output q
// aligned with lane's row-sum, epilogue LDS-free. K/V staging = v4-verbatim
// (gld_lds dbuf + source swizzle). LDS 32 KB; launch_bounds(256,3) — R6
// lesson: never cap VGPRs below demand (spill = 300 MB scratch writes).
__global__ __launch_bounds__(256, 3)
void flash_attn_mfma6(const unsigned short* __restrict__ Qb,
                      const unsigned short* __restrict__ Kb,
                      const unsigned short* __restrict__ Vt,
                      unsigned short* __restrict__ Ob)
{
    __shared__ __align__(16) unsigned short K_lds[2][64 * 64];    // 16 KB
    __shared__ __align__(16) unsigned short V_lds[2][64 * 64];    // 16 KB

    const int tid  = threadIdx.x;
    const int lane = tid & 63;
    const int wave = tid >> 6;
    const int lq   = lane & 31;          // this lane's q (and C-col) index
    const int hi   = lane >> 5;
    const int l7   = lane & 7;

    const int idx = blockIdx.x;
    const int qt = 15 - (idx >> 6);      // longest blocks dispatched first
    const int hb = idx & 63;
    const int h = hb & 15, b = hb >> 4;
    const int q0 = qt * 128;
    const long bh = (long)(b * NHEAD + h);
    const unsigned short* Kbh = Kb + bh * SEQT * HDIM;
    const unsigned short* Vbh = Vt + bh * HDIM * SEQT;
    const int ktiles = 2 * qt + 2;
    const int qg = q0 + wave * 32 + lq;  // this lane's global q row

    // staging geometry (v4-verified): rows r=tid>>3, r+32; 16B slot tid&7;
    // source slot pre-swizzled ^(r&7) (r+32 preserves r&7); LDS dest linear.
    const int r0 = tid >> 3;
    const int cs = (tid & 7) ^ (r0 & 7);

    // Q B-frags: B[k_d = c*16 + hi*8 + i][n=q] = Q[qg][c*16+hi*8+i]
    bf16x8 qf[4];
    {
        const unsigned short* qrow = Qb + (bh * SEQT + qg) * HDIM;
#pragma unroll
        for (int c = 0; c < 4; c++)
            qf[c] = *(const bf16x8*)(qrow + c * 16 + hi * 8);
    }

    // prologue: stage K/V tile 0 into buffer 0
    GLD_LDS16(Kbh + r0 * HDIM + cs * 8,              &K_lds[0][0] + tid * 8);
    GLD_LDS16(Kbh + (r0 + 32) * HDIM + cs * 8,       &K_lds[0][0] + 2048 + tid * 8);
    GLD_LDS16(Vbh + (long)r0 * SEQT + cs * 8,        &V_lds[0][0] + tid * 8);
    GLD_LDS16(Vbh + (long)(r0 + 32) * SEQT + cs * 8, &V_lds[0][0] + 2048 + tid * 8);

    f32x16 ot0 = {}, ot1 = {};           // O^T accs: d 0-31 / 32-63
    float rs = 0.f;

    for (int kt = 0; kt < ktiles; kt++) {
        const int cur = kt & 1;
        __builtin_amdgcn_s_waitcnt(0x0F70);   // vmcnt(0)
        __syncthreads();
        if (kt + 1 < ktiles) {
            const int k0n = (kt + 1) * 64, nxt = cur ^ 1;
            GLD_LDS16(Kbh + (k0n + r0) * HDIM + cs * 8,            &K_lds[nxt][0] + tid * 8);
            GLD_LDS16(Kbh + (k0n + r0 + 32) * HDIM + cs * 8,       &K_lds[nxt][0] + 2048 + tid * 8);
            GLD_LDS16(Vbh + (long)r0 * SEQT + k0n + cs * 8,        &V_lds[nxt][0] + tid * 8);
            GLD_LDS16(Vbh + (long)(r0 + 32) * SEQT + k0n + cs * 8, &V_lds[nxt][0] + 2048 + tid * 8);
        }

        const unsigned short* Kc = &K_lds[cur][0];
        const unsigned short* Vc = &V_lds[cur][0];

        // QK: st{0,1} = K(keys 0-31 / 32-63) . Q^T over d (4 chunks of 16)
        f32x16 st0 = {}, st1 = {};
        __builtin_amdgcn_s_setprio(1);
#pragma unroll
        for (int c = 0; c < 4; c++) {
            const int sl = ((2 * c + hi) ^ l7) * 8;     // phys slot (read swz)
            bf16x8 ka = *(const bf16x8*)&Kc[lq * 64 + sl];
            bf16x8 kb = *(const bf16x8*)&Kc[(lq + 32) * 64 + sl];
            st0 = __builtin_amdgcn_mfma_f32_32x32x16_bf16(ka, qf[c], st0, 0, 0, 0);
            st1 = __builtin_amdgcn_mfma_f32_32x32x16_bf16(kb, qf[c], st1, 0, 0, 0);
        }
        __builtin_amdgcn_s_setprio(0);

        if (kt >= 2 * qt) {                // diagonal tiles: mask key > q
            const int kbase = kt * 64;
#pragma unroll
            for (int r = 0; r < 16; r++) {
                const int rowl = (r & 3) + 8 * (r >> 2) + 4 * hi;
                if (kbase + rowl > qg)      st0[r] = -INFINITY;
                if (kbase + 32 + rowl > qg) st1[r] = -INFINITY;
            }
        }

        // p = exp2(s); scalar row-sum (lane owns one q)
#pragma unroll
        for (int r = 0; r < 16; r++) {
            st0[r] = __builtin_amdgcn_exp2f(st0[r]);
            st1[r] = __builtin_amdgcn_exp2f(st1[r]);
            rs += st0[r] + st1[r];
        }

        // PV: per key-chunk c (16 keys), build B-frag in regs, 2 mfma
#pragma unroll
        for (int c = 0; c < 4; c++) {
            const f32x16 ps = (c < 2) ? st0 : st1;      // compile-time select
            const int cc = (c & 1) * 8;
            // W[t][j]: packs of regs 8cc + t*4 + {2j,2j+1}
            unsigned W00 = pk2(ps[cc + 0], ps[cc + 1]);
            unsigned W01 = pk2(ps[cc + 2], ps[cc + 3]);
            unsigned W10 = pk2(ps[cc + 4], ps[cc + 5]);
            unsigned W11 = pk2(ps[cc + 6], ps[cc + 7]);
            // send W[1-h][*]; receive partner's W[h][*]
            unsigned s0 = hi ? W00 : W10;
            unsigned s1 = hi ? W01 : W11;
            unsigned x0 = (unsigned)__shfl_xor((int)s0, 32);
            unsigned x1 = (unsigned)__shfl_xor((int)s1, 32);
            union { unsigned u[4]; bf16x8 v; } pb;
            pb.u[0] = hi ? x0  : W00;    // keys 16c+8hi+{0,1}  (src half 0)
            pb.u[1] = hi ? x1  : W01;    // {2,3}
            pb.u[2] = hi ? W10 : x0;     // {4,5}               (src half 1)
            pb.u[3] = hi ? W11 : x1;     // {6,7}
            const int sl = ((2 * c + hi) ^ l7) * 8;
            bf16x8 va = *(const bf16x8*)&Vc[lq * 64 + sl];          // d 0-31
            bf16x8 vb = *(const bf16x8*)&Vc[(lq + 32) * 64 + sl];   // d 32-63
            __builtin_amdgcn_s_setprio(1);
            ot0 = __builtin_amdgcn_mfma_f32_32x32x16_bf16(va, pb.v, ot0, 0, 0, 0);
            ot1 = __builtin_amdgcn_mfma_f32_32x32x16_bf16(vb, pb.v, ot1, 0, 0, 0);
            __builtin_amdgcn_s_setprio(0);
        }
    }

    // row-sum across the two key-halves held by lane and lane^32
    rs += __shfl_xor(rs, 32);
    const float inv = 1.f / rs;

    // epilogue: lane owns q=qg; O[qg][d], d = (r&3)+8*(r>>2)+4hi+32dh
    unsigned short* orow = Ob + ((long)(b * SEQT + qg)) * EMBED + h * HDIM;
#pragma unroll
    for (int g = 0; g < 4; g++) {
        {
            const int d0 = 8 * g + 4 * hi;
            bf16x4 w;
#pragma unroll
            for (int e = 0; e < 4; e++) w[e] = (__bf16)(ot0[4 * g + e] * inv);
            *(bf16x4*)(orow + d0) = w;
        }
        {
            const int d0 = 32 + 8 * g + 4 * hi;
            bf16x4 w;
#pragma unroll
            for (int e = 0; e < 4; e++) w[e] = (__bf16)(ot1[4 * g + e] * inv);
            *(bf16x4*)(orow + d0) = w;
        }
    }
}

extern "C" void kernel_launch(void* const* d_in, const int* in_sizes, int n_in,
                              void* d_out, int out_size, void* d_ws, size_t ws_size,
                              hipStream_t stream)
{
    const float* x     = (const float*)d_in[0];
    const float* Wqkv  = (const float*)d_in[1];
    const float* bqkv  = (const float*)d_in[2];
    const float* Wproj = (const float*)d_in[3];
    const float* bproj = (const float*)d_in[4];
    float* out = (float*)d_out;

    const long Mbt = (long)BATCH * SEQT;                 // 8192
    const long per = (long)BATCH * NHEAD * SEQT * HDIM;  // 8,388,608 elems

    unsigned short* xb  = (unsigned short*)d_ws;
    unsigned short* wqb = xb  + per;
    unsigned short* wpb = wqb + 3 * EMBED * EMBED;
    unsigned short* Qb  = wpb + EMBED * EMBED;           // bf16 [bh][t][d], pre-scaled
    unsigned short* Kb  = Qb + per;
    unsigned short* Vt  = Kb + per;                      // bf16 [bh][d][t]
    unsigned short* Ob  = Vt + per;                      // bf16 [B,T,C]

    cvt_all<<<12288, 256, 0, stream>>>(x, Wqkv, Wproj, xb, wqb, wpb);

    dim3 g1(3 * EMBED / 128, Mbt / 128);
    gemm_bt_mfma<1><<<g1, 256, 0, stream>>>(xb, wqb, bqkv, Qb, Kb, Vt,
                                            (int)Mbt, 3 * EMBED, EMBED);

    flash_attn_mfma6<<<1024, 256, 0, stream>>>(Qb, Kb, Vt, Ob);

    dim3 g3(EMBED / 128, Mbt / 128);
    gemm_bt_mfma<0><<<g3, 256, 0, stream>>>(Ob, wpb, bproj, out, nullptr, nullptr,
                                            (int)Mbt, EMBED, EMBED);
}

// Round 8
// 252.660 us; speedup vs baseline: 1.5667x; 1.0167x over previous
//
#include <hip/hip_runtime.h>
#include <math.h>

#define EMBED 1024
#define NHEAD 16
#define HDIM  64
#define SEQT  2048
#define BATCH 4

typedef __bf16 bf16x4 __attribute__((ext_vector_type(4)));
typedef __bf16 bf16x8 __attribute__((ext_vector_type(8)));
typedef float  f32x4  __attribute__((ext_vector_type(4)));

#define AS1 __attribute__((address_space(1)))
#define AS3 __attribute__((address_space(3)))
// async global->LDS, 16B per lane (guide §5: width=16, m97-verified)
#define GLD_LDS16(gp, lp) __builtin_amdgcn_global_load_lds( \
    (const AS1 unsigned int*)(gp), (AS3 unsigned int*)(lp), 16, 0, 0)

// log2(e) / sqrt(HDIM): folded into Q at QKV-epilogue so scores are exp2-ready
#define QSCALE 0.180336880f

// native cast (v_cvt_pk_bf16_f32 on gfx950)
__device__ __forceinline__ unsigned short f2bf_hw(float f) {
    union { __bf16 h; unsigned short u; } c; c.h = (__bf16)f; return c.u;
}

// one launch converts x, W_qkv, W_proj (fp32 -> bf16), in float4 units.
// Grid-stride at 2048 blocks (G11): 6 units/thread, cuts ~10k workgroups of
// dispatch ramp vs the previous 12288-block launch. 3145728 units total
// (exactly 2048*256*6, no tail).
__global__ __launch_bounds__(256)
void cvt_all(const float* __restrict__ x, const float* __restrict__ wq,
             const float* __restrict__ wp,
             unsigned short* __restrict__ xb, unsigned short* __restrict__ wqb,
             unsigned short* __restrict__ wpb)
{
    const int N1 = 2097152;            // 8192*1024/4
    const int N2 = 786432;             // 3*1024*1024/4
    const int NT = 3145728;            // N1 + N2 + 262144
    for (int i = blockIdx.x * 256 + threadIdx.x; i < NT; i += 2048 * 256) {
        const float4* src; ushort4* dst; int j;
        if (i < N1)            { src = (const float4*)x;  dst = (ushort4*)xb;  j = i; }
        else if (i < N1 + N2)  { src = (const float4*)wq; dst = (ushort4*)wqb; j = i - N1; }
        else                   { src = (const float4*)wp; dst = (ushort4*)wpb; j = i - N1 - N2; }
        float4 v = src[j];
        ushort4 o;
        o.x = f2bf_hw(v.x); o.y = f2bf_hw(v.y); o.z = f2bf_hw(v.z); o.w = f2bf_hw(v.w);
        dst[j] = o;
    }
}

// ---------------- bf16 MFMA GEMM (R5: BK=64, frozen) ----------------
// 128x128 tile, BK=64, 2x2 waves, 4x4 accs x2 K-slices. 2-phase skeleton;
// family closed at ~550 TF (R4: conflicts off critical path; R5: sync
// frequency ~null; R1-R3: 8-phase ports all regressed). Do not touch.
template<int MODE>
__global__ __launch_bounds__(256)
void gemm_bt_mfma(const unsigned short* __restrict__ A, const unsigned short* __restrict__ Bw,
                  const float* __restrict__ bias,
                  void* out0, void* out1, void* out2,
                  int M, int N, int K)
{
    __shared__ __align__(16) unsigned short Asm[2][128 * 64];   // 2 x 16 KB
    __shared__ __align__(16) unsigned short Bsm[2][128 * 64];   // 2 x 16 KB

    const int tid  = threadIdx.x;
    const int lane = tid & 63;
    const int wave = tid >> 6;
    const int wm = wave >> 1, wn = wave & 1;
    const int col = lane & 15, quad = lane >> 4;
    const long m0 = (long)blockIdx.y * 128, n0 = (long)blockIdx.x * 128;

    f32x4 acc[4][4];
#pragma unroll
    for (int mi = 0; mi < 4; mi++)
#pragma unroll
        for (int ni = 0; ni < 4; ni++) acc[mi][ni] = (f32x4){0.f, 0.f, 0.f, 0.f};

    const int srow  = tid >> 3;                    // 0..31
    const int gslot = (tid & 7) ^ (srow & 7);      // pre-swizzled source slot
    const unsigned short* Ag = A  + (m0 + srow) * K + gslot * 8;
    const unsigned short* Bg = Bw + (n0 + srow) * K + gslot * 8;

#define STAGE(buf_, kk_) do { \
    _Pragma("unroll") for (int r_ = 0; r_ < 4; r_++) { \
        GLD_LDS16(Ag + (long)(r_ * 32) * K + (kk_), &Asm[buf_][0] + r_ * 2048 + tid * 8); \
        GLD_LDS16(Bg + (long)(r_ * 32) * K + (kk_), &Bsm[buf_][0] + r_ * 2048 + tid * 8); \
    } } while (0)

    const int cs0 = ((quad    ) ^ (col & 7)) * 8;  // K-slice 0
    const int cs1 = ((quad + 4) ^ (col & 7)) * 8;  // K-slice 1

    STAGE(0, 0);

    const int iters = K >> 6;
    for (int it = 0; it < iters; it++) {
        const int cur = it & 1;
        __builtin_amdgcn_s_waitcnt(0x0F70);   // vmcnt(0): tile `it` staged
        __syncthreads();
        if (it + 1 < iters)
            STAGE(cur ^ 1, (it + 1) * 64);

        bf16x8 af[4][2], bf[4][2];
#pragma unroll
        for (int mi = 0; mi < 4; mi++) {
            const int row = wm * 64 + mi * 16 + col;
            af[mi][0] = *(const bf16x8*)&Asm[cur][row * 64 + cs0];
            af[mi][1] = *(const bf16x8*)&Asm[cur][row * 64 + cs1];
        }
#pragma unroll
        for (int ni = 0; ni < 4; ni++) {
            const int row = wn * 64 + ni * 16 + col;
            bf[ni][0] = *(const bf16x8*)&Bsm[cur][row * 64 + cs0];
            bf[ni][1] = *(const bf16x8*)&Bsm[cur][row * 64 + cs1];
        }
#pragma unroll
        for (int mi = 0; mi < 4; mi++)
#pragma unroll
            for (int ni = 0; ni < 4; ni++) {
                acc[mi][ni] = __builtin_amdgcn_mfma_f32_16x16x32_bf16(af[mi][0], bf[ni][0], acc[mi][ni], 0, 0, 0);
                acc[mi][ni] = __builtin_amdgcn_mfma_f32_16x16x32_bf16(af[mi][1], bf[ni][1], acc[mi][ni], 0, 0, 0);
            }
    }
#undef STAGE

    // epilogue: C/D layout col=lane&15, row=quad*4+r (m89/m91-verified)
#pragma unroll
    for (int mi = 0; mi < 4; mi++) {
#pragma unroll
        for (int ni = 0; ni < 4; ni++) {
            long n = n0 + wn * 64 + ni * 16 + col;
            float bv = bias[n];
#pragma unroll
            for (int r = 0; r < 4; r++) {
                long m = m0 + wm * 64 + mi * 16 + quad * 4 + r;
                float v = acc[mi][ni][r] + bv;
                if (MODE == 0) {
                    ((float*)out0)[m * N + n] = v;
                } else {
                    int which = (int)(n >> 10);
                    int c = (int)(n & 1023);
                    int h = c >> 6, d = c & 63;
                    int b = (int)(m >> 11), t = (int)(m & 2047);
                    long bh = (long)(b * NHEAD + h);
                    if (which == 0)      ((unsigned short*)out0)[(bh * SEQT + t) * HDIM + d] = f2bf_hw(v * QSCALE);
                    else if (which == 1) ((unsigned short*)out1)[(bh * SEQT + t) * HDIM + d] = f2bf_hw(v);
                    else                 ((unsigned short*)out2)[(bh * HDIM + d) * SEQT + t] = f2bf_hw(v);
                }
            }
        }
    }
}

// ---------------- bf16 MFMA flash attention (R5-verified v4 + causal skip) -------
// Q-tile 128; 4 waves × 32 q-rows. No-max softmax; S computed transposed
// (mfma(K,Q)) -> packed b64 P stores; P stored [q][k] for b128 PV A-frag reads.
// T5 setprio around MFMA clusters (R4/R5, neutral-harmless).
// CAUSAL SKIP (new): on the final diagonal tile (kt=2qt+1) the whole key range
// exceeds waves 0-1's q rows -> their P contribution is exactly exp2(-inf)=0.
// Skip the compute body when k0 > q0+wave*32+31 (wave-uniform branch, no
// divergence; P_lds rows are wave-private and unread when skipped; barriers
// and staging still executed by all waves -> bit-identical output).
#define PPAD 72

__global__ __launch_bounds__(256, 3)
void flash_attn_mfma4(const unsigned short* __restrict__ Qb,
                      const unsigned short* __restrict__ Kb,
                      const unsigned short* __restrict__ Vt,
                      unsigned short* __restrict__ Ob)
{
    __shared__ __align__(16) unsigned short P_lds[128 * PPAD];    // [q][k] 18432 B
    __shared__ __align__(16) unsigned short K_lds[2][64 * 64];    // 16 KB
    __shared__ __align__(16) unsigned short V_lds[2][64 * 64];    // 16 KB
    __shared__ __align__(16) float L_lds[128];                    // row sums

    const int tid  = threadIdx.x;
    const int lane = tid & 63;
    const int wave = tid >> 6;
    const int col  = lane & 15;
    const int quad = lane >> 4;

    const int idx = blockIdx.x;
    const int qt = 15 - (idx >> 6);      // longest blocks dispatched first
    const int hb = idx & 63;
    const int h = hb & 15, b = hb >> 4;
    const int q0 = qt * 128;
    const long bh = (long)(b * NHEAD + h);
    const unsigned short* Kbh = Kb + bh * SEQT * HDIM;
    const unsigned short* Vbh = Vt + bh * HDIM * SEQT;
    const int ktiles = 2 * qt + 2;

    const int r0 = tid >> 3,         c0 = (tid & 7) ^ (r0 & 7);
    const int r1 = (tid + 256) >> 3, c1 = (tid & 7) ^ (r1 & 7);

    bf16x8 qf[2][2];
#pragma unroll
    for (int ni = 0; ni < 2; ni++) {
        const unsigned short* qrow = Qb + (bh * SEQT + q0 + wave * 32 + ni * 16 + col) * HDIM;
        qf[ni][0] = *(const bf16x8*)(qrow + quad * 8);
        qf[ni][1] = *(const bf16x8*)(qrow + 32 + quad * 8);
    }

    GLD_LDS16(Kbh + r0 * HDIM + c0 * 8,        &K_lds[0][0] + tid * 8);
    GLD_LDS16(Kbh + r1 * HDIM + c1 * 8,        &K_lds[0][0] + 2048 + tid * 8);
    GLD_LDS16(Vbh + (long)r0 * SEQT + c0 * 8,  &V_lds[0][0] + tid * 8);
    GLD_LDS16(Vbh + (long)r1 * SEQT + c1 * 8,  &V_lds[0][0] + 2048 + tid * 8);

    f32x4 o[2][4];
#pragma unroll
    for (int mi = 0; mi < 2; mi++)
#pragma unroll
        for (int dt = 0; dt < 4; dt++) o[mi][dt] = (f32x4){0.f, 0.f, 0.f, 0.f};
    float rs[2] = {0.f, 0.f};

    const int cswz0 = quad ^ (col & 7);
    const int cswz1 = (quad + 4) ^ (col & 7);

    for (int kt = 0; kt < ktiles; kt++) {
        const int cur = kt & 1;
        const int k0 = kt * 64;
        __builtin_amdgcn_s_waitcnt(0x0F70);   // vmcnt(0)
        __syncthreads();
        if (kt + 1 < ktiles) {
            const int k0n = (kt + 1) * 64, nxt = cur ^ 1;
            GLD_LDS16(Kbh + (k0n + r0) * HDIM + c0 * 8,       &K_lds[nxt][0] + tid * 8);
            GLD_LDS16(Kbh + (k0n + r1) * HDIM + c1 * 8,       &K_lds[nxt][0] + 2048 + tid * 8);
            GLD_LDS16(Vbh + (long)r0 * SEQT + k0n + c0 * 8,   &V_lds[nxt][0] + tid * 8);
            GLD_LDS16(Vbh + (long)r1 * SEQT + k0n + c1 * 8,   &V_lds[nxt][0] + 2048 + tid * 8);
        }

        // causal skip: whole tile masked for this wave (kt=2qt+1, waves 0-1)
        if (k0 > q0 + wave * 32 + 31) continue;

        // S^T = K Q^T : A = K (m=key), B = Q (n=query). C: col=q, row=key.
        const unsigned short* Kc = &K_lds[cur][0];
        f32x4 st[4][2];
        __builtin_amdgcn_s_setprio(1);
#pragma unroll
        for (int mt = 0; mt < 4; mt++) {
            const int row = mt * 16 + col;
            bf16x8 kf0 = *(const bf16x8*)&Kc[row * 64 + cswz0 * 8];
            bf16x8 kf1 = *(const bf16x8*)&Kc[row * 64 + cswz1 * 8];
#pragma unroll
            for (int ni = 0; ni < 2; ni++) {
                f32x4 acc = (f32x4){0.f, 0.f, 0.f, 0.f};
                acc = __builtin_amdgcn_mfma_f32_16x16x32_bf16(kf0, qf[ni][0], acc, 0, 0, 0);
                acc = __builtin_amdgcn_mfma_f32_16x16x32_bf16(kf1, qf[ni][1], acc, 0, 0, 0);
                st[mt][ni] = acc;
            }
        }
        __builtin_amdgcn_s_setprio(0);
        if (kt >= 2 * qt) {                // diagonal tiles: mask key > q
#pragma unroll
            for (int mt = 0; mt < 4; mt++) {
                const int keybase = k0 + mt * 16 + quad * 4;
#pragma unroll
                for (int ni = 0; ni < 2; ni++) {
                    const int qg = q0 + wave * 32 + ni * 16 + col;
#pragma unroll
                    for (int r = 0; r < 4; r++)
                        if (keybase + r > qg) st[mt][ni][r] = -INFINITY;
                }
            }
        }

        // p = exp2(s); accumulate row-sum partials; packed b64 P-store
#pragma unroll
        for (int mt = 0; mt < 4; mt++)
#pragma unroll
            for (int ni = 0; ni < 2; ni++) {
                f32x4 p;
#pragma unroll
                for (int r = 0; r < 4; r++) p[r] = __builtin_amdgcn_exp2f(st[mt][ni][r]);
                rs[ni] += (p[0] + p[1]) + (p[2] + p[3]);
                bf16x4 pb = __builtin_convertvector(p, bf16x4);
                *(bf16x4*)&P_lds[(wave * 32 + ni * 16 + col) * PPAD + mt * 16 + quad * 4] = pb;
            }

        // PV: A = P[q][k] (wave-private rows), B = V^T
        const unsigned short* Vc = &V_lds[cur][0];
        __builtin_amdgcn_s_setprio(1);
#pragma unroll
        for (int mi = 0; mi < 2; mi++) {
            const unsigned short* prow = &P_lds[(wave * 32 + mi * 16 + col) * PPAD];
            bf16x8 pf0 = *(const bf16x8*)(prow + quad * 8);
            bf16x8 pf1 = *(const bf16x8*)(prow + 32 + quad * 8);
#pragma unroll
            for (int dt = 0; dt < 4; dt++) {
                const int row = dt * 16 + col;
                bf16x8 vf0 = *(const bf16x8*)&Vc[row * 64 + cswz0 * 8];
                bf16x8 vf1 = *(const bf16x8*)&Vc[row * 64 + cswz1 * 8];
                o[mi][dt] = __builtin_amdgcn_mfma_f32_16x16x32_bf16(pf0, vf0, o[mi][dt], 0, 0, 0);
                o[mi][dt] = __builtin_amdgcn_mfma_f32_16x16x32_bf16(pf1, vf1, o[mi][dt], 0, 0, 0);
            }
        }
        __builtin_amdgcn_s_setprio(0);
    }

    // final row-sum reduction over quads (partials partitioned by quad)
#pragma unroll
    for (int ni = 0; ni < 2; ni++) {
        rs[ni] += __shfl_xor(rs[ni], 16);
        rs[ni] += __shfl_xor(rs[ni], 32);
        if (quad == 0) L_lds[wave * 32 + ni * 16 + col] = rs[ni];
    }
    __syncthreads();
    f32x4 lf[2];
#pragma unroll
    for (int mi = 0; mi < 2; mi++)
        lf[mi] = *(const f32x4*)&L_lds[wave * 32 + mi * 16 + quad * 4];

    // epilogue: bf16 Ob[b][t][h*64+d]
#pragma unroll
    for (int mi = 0; mi < 2; mi++)
#pragma unroll
        for (int r = 0; r < 4; r++) {
            float inv = 1.f / lf[mi][r];
            int t = q0 + wave * 32 + mi * 16 + quad * 4 + r;
            unsigned short* orow = Ob + ((long)(b * SEQT + t)) * EMBED + h * HDIM;
#pragma unroll
            for (int dt = 0; dt < 4; dt++)
                orow[dt * 16 + col] = f2bf_hw(o[mi][dt][r] * inv);
        }
}

extern "C" void kernel_launch(void* const* d_in, const int* in_sizes, int n_in,
                              void* d_out, int out_size, void* d_ws, size_t ws_size,
                              hipStream_t stream)
{
    const float* x     = (const float*)d_in[0];
    const float* Wqkv  = (const float*)d_in[1];
    const float* bqkv  = (const float*)d_in[2];
    const float* Wproj = (const float*)d_in[3];
    const float* bproj = (const float*)d_in[4];
    float* out = (float*)d_out;

    const long Mbt = (long)BATCH * SEQT;                 // 8192
    const long per = (long)BATCH * NHEAD * SEQT * HDIM;  // 8,388,608 elems

    unsigned short* xb  = (unsigned short*)d_ws;
    unsigned short* wqb = xb  + per;
    unsigned short* wpb = wqb + 3 * EMBED * EMBED;
    unsigned short* Qb  = wpb + EMBED * EMBED;           // bf16 [bh][t][d], pre-scaled
    unsigned short* Kb  = Qb + per;
    unsigned short* Vt  = Kb + per;                      // bf16 [bh][d][t]
    unsigned short* Ob  = Vt + per;                      // bf16 [B,T,C]

    cvt_all<<<2048, 256, 0, stream>>>(x, Wqkv, Wproj, xb, wqb, wpb);

    dim3 g1(3 * EMBED / 128, Mbt / 128);
    gemm_bt_mfma<1><<<g1, 256, 0, stream>>>(xb, wqb, bqkv, Qb, Kb, Vt,
                                            (int)Mbt, 3 * EMBED, EMBED);

    flash_attn_mfma4<<<1024, 256, 0, stream>>>(Qb, Kb, Vt, Ob);

    dim3 g3(EMBED / 128, Mbt / 128);
    gemm_bt_mfma<0><<<g3, 256, 0, stream>>>(Ob, wpb, bproj, out, nullptr, nullptr,
                                            (int)Mbt, EMBED, EMBED);
}